// Round 10
// baseline (957.488 us; speedup 1.0000x reference)
//
#include <hip/hip_runtime.h>
#include <stddef.h>

typedef unsigned short u16;
typedef unsigned int u32;

#define B_ 4
#define T_ 2048
#define C_ 1024
#define E_ 8
#define H_ 4096
#define NTOK (B_ * T_)     // 8192
#define NPAIR (NTOK * 2)   // 16384
#define BM 128
#define BN 128
#define BK 64              // k-tile (bf16 elements); row = 128 B
#define KSPLIT 2           // phase2 K-split (atomics make this free)
#define MAXTILES 136       // ceil((16384 + 8*127)/128)
#define MAXROWS (MAXTILES * 128)  // 17408
#define NWG1 ((H_ / BN) * MAXTILES)  // 4352 gemm1 blocks

// gemm1_conv appended segments
#define NB_C2 2048   // convert W2
#define NB_CP 1024   // out = x copy (8192 floats/block)

// fused_pre block-range partition
#define NB_C1 2048   // convert W1: (4096/256) x (1024/64) x 8
#define NB_LN NTOK   // 8192
#define NB_CNT (NPAIR / 256)  // 64
#define NB_TID (MAXROWS / 1024)  // 17
#define NB_TOTAL (NB_C1 + NB_LN + NB_CNT + NB_TID)

typedef __bf16 bf16x8 __attribute__((ext_vector_type(8)));
typedef float f32x4 __attribute__((ext_vector_type(4)));
typedef u16 u16x8 __attribute__((ext_vector_type(8)));

__device__ __forceinline__ u16 f2bf(float f) {
    union { float f; u32 u; } c;
    c.f = f;
    u32 r = c.u + 0x7FFFu + ((c.u >> 16) & 1u);  // round-to-nearest-even
    return (u16)(r >> 16);
}

// pack two floats to bf16x2 in a u32 via native RNE casts (compiler can fuse
// to v_cvt_pk_bf16_f32)
__device__ __forceinline__ u32 pk2bf(float a, float b) {
    union { __bf16 h; u16 u; } x, y;
    x.h = (__bf16)a;
    y.h = (__bf16)b;
    return (u32)x.u | ((u32)y.u << 16);
}

// async global->LDS, 16B per lane; LDS dest = wave-uniform base + lane*16
__device__ __forceinline__ void gld16(const void* g, void* l) {
    __builtin_amdgcn_global_load_lds(
        (const __attribute__((address_space(1))) u32*)g,
        (__attribute__((address_space(3))) u32*)l, 16, 0, 0);
}

// ---------------- streaming bodies -------------------------------------------

// LayerNorm: h = bf16(LN(x)). The out=x residual copy lives in gemm1_conv.
__device__ __forceinline__ void ln_body(
    const float* __restrict__ x, const float* __restrict__ gamma,
    const float* __restrict__ beta, u16* __restrict__ h, int token,
    float* smf) {
    const int t = threadIdx.x;
    const float* xr = x + (size_t)token * C_;
    float4 v = *(const float4*)(xr + t * 4);
    float s = v.x + v.y + v.z + v.w;
    float ss = v.x * v.x + v.y * v.y + v.z * v.z + v.w * v.w;
    #pragma unroll
    for (int off = 32; off > 0; off >>= 1) {
        s += __shfl_down(s, off);
        ss += __shfl_down(ss, off);
    }
    float* ws_s = smf;       // [4]
    float* ws_q = smf + 4;   // [4]
    const int wave = t >> 6, lane = t & 63;
    if (lane == 0) { ws_s[wave] = s; ws_q[wave] = ss; }
    __syncthreads();
    float S = ws_s[0] + ws_s[1] + ws_s[2] + ws_s[3];
    float Q = ws_q[0] + ws_q[1] + ws_q[2] + ws_q[3];
    float mu = S * (1.0f / C_);
    float var = Q * (1.0f / C_) - mu * mu;
    float rstd = rsqrtf(var + 1e-5f);
    float4 g = *(const float4*)(gamma + t * 4);
    float4 b = *(const float4*)(beta + t * 4);
    ushort4 hv;
    hv.x = f2bf((v.x - mu) * rstd * g.x + b.x);
    hv.y = f2bf((v.y - mu) * rstd * g.y + b.y);
    hv.z = f2bf((v.z - mu) * rstd * g.z + b.z);
    hv.w = f2bf((v.w - mu) * rstd * g.w + b.w);
    *(ushort4*)(h + (size_t)token * C_ + t * 4) = hv;
}

// Weight convert+transpose fp32 [E][K][N] -> bf16 [E][N][K], streaming tiles
// of 64 k-rows x 256 n-cols (1KB contiguous wave reads, 8x128B row writes,
// conflict-free pitch-258 LDS; u32-packed LDS writes). PERM: src k-row
// permuted per 64-block by phi(r)=((r&3)<<4)|(r>>2) (W2 only).
template <bool PERM>
__device__ __forceinline__ void conv_body(
    const float* __restrict__ in, u16* __restrict__ outp, int K, int N,
    int bid, u16* sm) {
    const int nbx = N >> 8;              // N/256
    const int nby = K >> 6;              // K/64
    const int bx = bid % nbx;
    const int by = (bid / nbx) % nby;
    const int e = bid / (nbx * nby);
    const int k0 = by * 64, n0 = bx * 256;
    const int t = threadIdx.x;
    const float* src = in + (size_t)e * K * N;
    u16* dst = outp + (size_t)e * N * K;
    const int cw = t & 63;        // n-chunk (float4) within row
    const int rw = t >> 6;        // wave index = row offset within pass
    #pragma unroll
    for (int p = 0; p < 16; ++p) {
        const int r = p * 4 + rw;
        const int kr = PERM ? (((r & 3) << 4) | (r >> 2)) : r;
        float4 v = *(const float4*)(src + (size_t)(k0 + kr) * N + n0 + cw * 4);
        const int base = r * 258 + cw * 4;  // u16 idx; byte addr 4-B aligned
        *(u32*)&sm[base + 0] = pk2bf(v.x, v.y);
        *(u32*)&sm[base + 2] = pk2bf(v.z, v.w);
    }
    __syncthreads();
    const u32* smw = (const u32*)sm;
    const int c = t & 7;          // 16B k-chunk within a dst row
    const int ro = t >> 3;        // row-pair offset within pass (0..31)
    #pragma unroll
    for (int p = 0; p < 4; ++p) {
        const int np = p * 32 + ro;          // dst rows 2np, 2np+1
        u16x8 lo, hi;
        #pragma unroll
        for (int m = 0; m < 8; ++m) {
            u32 wv = smw[(c * 8 + m) * 129 + np];
            lo[m] = (u16)(wv & 0xFFFFu);
            hi[m] = (u16)(wv >> 16);
        }
        *(u16x8*)(dst + (size_t)(n0 + 2 * np) * K + k0 + c * 8) = lo;
        *(u16x8*)(dst + (size_t)(n0 + 2 * np + 1) * K + k0 + c * 8) = hi;
    }
}

// Expert count: LDS histogram, 8 global atomics per block.
__device__ __forceinline__ void count_body(
    const int* __restrict__ winners, int* __restrict__ counts, int b, int* lc) {
    if (threadIdx.x < E_) lc[threadIdx.x] = 0;
    __syncthreads();
    atomicAdd(&lc[winners[b * 256 + threadIdx.x]], 1);  // LDS atomic
    __syncthreads();
    if (threadIdx.x < E_) {
        int c = lc[threadIdx.x];
        if (c) atomicAdd(&counts[threadIdx.x], c);
    }
}

// out = x residual copy: 8192 floats (2048 float4) per block.
__device__ __forceinline__ void copy_body(
    const float* __restrict__ x, float* __restrict__ out, int b) {
    const int t = threadIdx.x;
    const float4* src = (const float4*)x + (size_t)b * 2048;
    float4* dst = (float4*)out + (size_t)b * 2048;
    #pragma unroll
    for (int i = 0; i < 8; ++i) dst[i * 256 + t] = src[i * 256 + t];
}

// ---------------- fused_pre: conv-W1 + LN + count + token_id fill ------------
__global__ __launch_bounds__(256) void fused_pre(
    const float* __restrict__ x, const float* __restrict__ gamma,
    const float* __restrict__ beta, u16* __restrict__ h,
    const int* __restrict__ winners, int* __restrict__ counts,
    const float* __restrict__ W1, u16* __restrict__ W1T,
    int* __restrict__ token_id) {
    __shared__ u16 sm[64 * 258];  // conv buffer; reused by ln (floats) & count
    int b = blockIdx.x;
    if (b < NB_C1) { conv_body<false>(W1, W1T, C_, H_, b, sm); return; }
    b -= NB_C1;
    if (b < NB_LN) { ln_body(x, gamma, beta, h, b, (float*)sm); return; }
    b -= NB_LN;
    if (b < NB_CNT) { count_body(winners, counts, b, (int*)sm); return; }
    b -= NB_CNT;
    const int p = (b * 256 + threadIdx.x) * 4;  // token_id = -1 fill
    if (p < MAXROWS) *(int4*)(token_id + p) = make_int4(-1, -1, -1, -1);
}

// ---------------- Placement: block-aggregated reservation --------------------
__global__ __launch_bounds__(256) void place_kernel(
    const int* __restrict__ winners, const float* __restrict__ wts,
    const int* __restrict__ counts, int* __restrict__ pos,
    int* __restrict__ token_id, float* __restrict__ pair_w,
    int* __restrict__ tile_expert) {
    __shared__ int po[E_ + 1];
    __shared__ int lcount[E_], lbase[E_];
    const int t = threadIdx.x;
    if (t < E_) lcount[t] = 0;
    if (t == 0) {
        int off = 0;
        po[0] = 0;
        #pragma unroll
        for (int e = 0; e < E_; ++e) {
            off += ((counts[e] + 127) >> 7) << 7;
            po[e + 1] = off;
        }
    }
    __syncthreads();
    if (blockIdx.x == 0 && t < MAXTILES) {
        int r = t * 128;
        int ee = -1;
        if (r < po[E_]) {
            ee = 0;
            while (r >= po[ee + 1]) ++ee;
        }
        tile_expert[t] = ee;
    }
    const int p = blockIdx.x * 256 + t;
    const int e = winners[p];
    const int rank = atomicAdd(&lcount[e], 1);  // LDS atomic
    __syncthreads();
    if (t < E_) {
        int c = lcount[t];
        lbase[t] = c ? atomicAdd(&pos[t], c) : 0;
    }
    __syncthreads();
    const int slot = po[e] + lbase[e] + rank;
    token_id[slot] = p >> 1;
    pair_w[slot] = wts[p];
}

// ---------------- Grouped GEMM body (round-2/4/5 proven, unchanged) ----------
// m97-style async staging + XOR swizzle, implicit wave overlap,
// T1 XCD-bijective swizzle, PHASE2 K-split.
// PHASE2=false: hidden[r,:] = bf16(relu(h[tok(r)] @ W1T[e]^T)^2)  K=1024, N=4096
//               hidden K-dim stored permuted: p64 = lrow*4 + ni
// PHASE2=true : out[tok(r),:] += pair_w[r] * (hidden[r] @ W2T[e]^T) K=4096/KSPLIT
template <bool PHASE2>
__device__ __forceinline__ void gemm_body(
    const u16* __restrict__ Amat, const u16* __restrict__ Bmat,
    const int* __restrict__ token_id, const float* __restrict__ pair_w,
    const int* __restrict__ tile_expert, u16* __restrict__ hidden,
    float* __restrict__ out, const u16* __restrict__ zeropage,
    int bid0, int zi, u16* __restrict__ As, u16* __restrict__ Bs) {
    constexpr int Kdim = PHASE2 ? H_ : C_;            // row pitch of A and B
    constexpr int KRANGE = PHASE2 ? (H_ / KSPLIT) : C_;  // per-block K extent
    constexpr int NWGX = PHASE2 ? (C_ / BN) : (H_ / BN); // 8 or 32
    constexpr int NWG = NWGX * MAXTILES;              // 1088 or 4352 (%8==0)

    int bid = (bid0 & 7) * (NWG >> 3) + (bid0 >> 3);
    const int ct = bid % NWGX;
    const int rt = bid / NWGX;

    const int e = tile_expert[rt];
    if (e < 0) return;
    const int tid = threadIdx.x;
    const int w = tid >> 6;      // wave 0..3
    const int lane = tid & 63;
    const int n0 = ct * BN;
    const int kbase = PHASE2 ? zi * KRANGE : 0;
    const u16* Bb = Bmat + (size_t)e * H_ * C_;

    const int sub = lane >> 3;
    const size_t koffB = (size_t)(((lane & 7) ^ sub) * 16);

    const char* abase[4];
    bool aval[4];
    const char* bbase[4];
    u16* adst[4];
    u16* bdst[4];
    #pragma unroll
    for (int j = 0; j < 4; ++j) {
        const int lrow32 = w * 32 + j * 8 + sub;
        const int grow = rt * BM + lrow32;
        if (PHASE2) {
            aval[j] = true;
            abase[j] = (const char*)(Amat + (size_t)grow * Kdim + kbase) + koffB;
        } else {
            int tok = token_id[grow];
            aval[j] = tok >= 0;
            abase[j] = (const char*)(Amat + (size_t)(tok < 0 ? 0 : tok) * Kdim) + koffB;
        }
        bbase[j] = (const char*)(Bb + (size_t)(n0 + lrow32) * Kdim + kbase) + koffB;
        adst[j] = &As[(w * 32 + j * 8) * BK];
        bdst[j] = &Bs[(w * 32 + j * 8) * BK];
    }

    const int wr = w >> 1, wc = w & 1;
    const int lrow = lane & 15;
    const int quad = lane >> 4;
    const int rsw = lrow & 7;  // read-side swizzle key

    f32x4 acc[4][4] = {};

    for (int k0 = 0; k0 < KRANGE; k0 += BK) {
        __syncthreads();
        const size_t kb = (size_t)k0 * 2;
        #pragma unroll
        for (int j = 0; j < 4; ++j)
            gld16(aval[j] ? abase[j] + kb : (const char*)zeropage, adst[j]);
        #pragma unroll
        for (int j = 0; j < 4; ++j)
            gld16(bbase[j] + kb, bdst[j]);
        __syncthreads();
        #pragma unroll
        for (int kk = 0; kk < 2; ++kk) {
            bf16x8 af[4], bfv[4];
            #pragma unroll
            for (int mi = 0; mi < 4; ++mi) {
                int row = wr * 64 + mi * 16 + lrow;
                int pch = (kk * 4 + quad) ^ rsw;
                af[mi] = *(const bf16x8*)&As[row * BK + pch * 8];
            }
            #pragma unroll
            for (int ni = 0; ni < 4; ++ni) {
                int row = wc * 64 + ni * 16 + lrow;
                int pch = (kk * 4 + quad) ^ rsw;
                bfv[ni] = *(const bf16x8*)&Bs[row * BK + pch * 8];
            }
            #pragma unroll
            for (int mi = 0; mi < 4; ++mi)
                #pragma unroll
                for (int ni = 0; ni < 4; ++ni)
                    acc[mi][ni] = __builtin_amdgcn_mfma_f32_16x16x32_bf16(
                        af[mi], bfv[ni], acc[mi][ni], 0, 0, 0);
        }
    }

    if (!PHASE2) {
        #pragma unroll
        for (int mi = 0; mi < 4; ++mi) {
            int rbase = rt * BM + wr * 64 + mi * 16 + quad * 4;
            #pragma unroll
            for (int j = 0; j < 4; ++j) {
                ushort4 o;
                float v0 = fmaxf(acc[mi][0][j], 0.0f);
                float v1 = fmaxf(acc[mi][1][j], 0.0f);
                float v2 = fmaxf(acc[mi][2][j], 0.0f);
                float v3 = fmaxf(acc[mi][3][j], 0.0f);
                o.x = f2bf(v0 * v0);
                o.y = f2bf(v1 * v1);
                o.z = f2bf(v2 * v2);
                o.w = f2bf(v3 * v3);
                *(ushort4*)&hidden[(size_t)(rbase + j) * H_ + n0 + wc * 64 + lrow * 4] = o;
            }
        }
    } else {
        #pragma unroll
        for (int mi = 0; mi < 4; ++mi) {
            int rbase = rt * BM + wr * 64 + mi * 16 + quad * 4;
            #pragma unroll
            for (int j = 0; j < 4; ++j) {
                int grow = rbase + j;
                int tok = token_id[grow];
                if (tok < 0) continue;
                float pw = pair_w[grow];
                #pragma unroll
                for (int ni = 0; ni < 4; ++ni) {
                    int col = n0 + wc * 64 + ni * 16 + lrow;
                    atomicAdd(&out[(size_t)tok * C_ + col], pw * acc[mi][ni][j]);
                }
            }
        }
    }
}

// ---------------- gemm1 + conv-W2 + out=x soak (horizontal fusion) -----------
// conv-W2 and the residual copy only gate gemm2; gemm1 uses ~16% of HBM BW,
// so their ~256 MB streams free under gemm1's compute. LDS union 33 KB.
__global__ __launch_bounds__(256, 4) void gemm1_conv(
    const u16* __restrict__ h, const u16* __restrict__ W1T,
    const int* __restrict__ token_id, const float* __restrict__ pair_w,
    const int* __restrict__ tile_expert, u16* __restrict__ hidden,
    const u16* __restrict__ zeropage, const float* __restrict__ W2,
    u16* __restrict__ W2T, const float* __restrict__ x,
    float* __restrict__ out) {
    __shared__ u16 smu[64 * 258];  // 33 KB union: gemm uses first 32 KB
    const int b = blockIdx.x;
    if (b < NWG1) {
        gemm_body<false>(h, W1T, token_id, pair_w, tile_expert, hidden,
                         nullptr, zeropage, b, 0, smu, smu + BM * BK);
    } else if (b < NWG1 + NB_C2) {
        conv_body<true>(W2, W2T, H_, C_, b - NWG1, smu);
    } else {
        copy_body(x, out, b - NWG1 - NB_C2);
    }
}

// ---------------- phase2: LB(256,5) -> 5 blocks/CU ---------------------------
// gemm2's LDS is exactly 32 KB: 5 x 32768 = 163840 B = the full 160 KiB LDS/CU,
// and VGPR=60 -> 5 blocks x 4 waves x 60 = 300/SIMD <= 512. 5 blocks/CU gives
// +25% TLP for the latency-hiding regime this 2-barrier loop relies on, and
// improves the tail: 2176 blocks / 1280 concurrent = 85% util (vs 71% at 4/CU).
__global__ __launch_bounds__(256, 5) void gemm2_kernel(
    const u16* __restrict__ hidden, const u16* __restrict__ W2T,
    const int* __restrict__ token_id, const float* __restrict__ pair_w,
    const int* __restrict__ tile_expert, float* __restrict__ out,
    const u16* __restrict__ zeropage) {
    __shared__ u16 As[BM * BK];
    __shared__ u16 Bs[BN * BK];
    const int bid = blockIdx.y * (C_ / BN) + blockIdx.x;
    gemm_body<true>(hidden, W2T, token_id, pair_w, tile_expert, nullptr, out,
                    zeropage, bid, blockIdx.z, As, Bs);
}

// ---------------- Launch ----------------
extern "C" void kernel_launch(void* const* d_in, const int* in_sizes, int n_in,
                              void* d_out, int out_size, void* d_ws, size_t ws_size,
                              hipStream_t stream) {
    const float* x = (const float*)d_in[0];
    const float* weights = (const float*)d_in[1];
    const float* gamma = (const float*)d_in[2];
    const float* beta = (const float*)d_in[3];
    const float* W1 = (const float*)d_in[4];
    const float* W2 = (const float*)d_in[5];
    const int* winners = (const int*)d_in[6];
    float* out = (float*)d_out;

    char* ws = (char*)d_ws;
    const size_t SZ_H = (size_t)NTOK * C_ * 2;           // 16 MB
    const size_t SZ_HID = (size_t)MAXROWS * H_ * 2;      // 136 MB
    const size_t SZ_WT = (size_t)E_ * H_ * C_ * 2;       // 64 MB each
    const size_t OFF_HID = SZ_H;
    const size_t OFF_W1T = OFF_HID + SZ_HID;
    const size_t OFF_W2T = OFF_W1T + SZ_WT;
    const size_t OFF_META = OFF_W2T + SZ_WT;

    u16* h = (u16*)ws;
    u16* hidden = (u16*)(ws + OFF_HID);
    u16* W1T = (u16*)(ws + OFF_W1T);
    u16* W2T = (u16*)(ws + OFF_W2T);
    int* meta = (int*)(ws + OFF_META);
    int* counts = meta;            // [0,8)
    int* pos = meta + 8;           // [8,16)
    // [16,32) reserved
    u16* zeropage = (u16*)(meta + 32);  // [32,48) 64 B, 16B-aligned
    int* tile_expert = meta + 48;  // [48,184)
    int* token_id = meta + 192;
    float* pair_w = (float*)(meta + 192 + MAXROWS);

    hipMemsetAsync(meta, 0, 192 * sizeof(int), stream);

    fused_pre<<<NB_TOTAL, 256, 0, stream>>>(x, gamma, beta, h, winners,
                                            counts, W1, W1T, token_id);
    place_kernel<<<NPAIR / 256, 256, 0, stream>>>(winners, weights, counts, pos,
                                                  token_id, pair_w, tile_expert);
    gemm1_conv<<<NWG1 + NB_C2 + NB_CP, 256, 0, stream>>>(
        h, W1T, token_id, pair_w, tile_expert, hidden, zeropage, W2, W2T, x, out);
    gemm2_kernel<<<dim3(C_ / BN, MAXTILES, KSPLIT), 256, 0, stream>>>(
        hidden, W2T, token_id, pair_w, tile_expert, out, zeropage);
}

// Round 11
// 702.121 us; speedup vs baseline: 1.3637x; 1.3637x over previous
//
#include <hip/hip_runtime.h>
#include <stddef.h>

typedef unsigned short u16;
typedef unsigned int u32;

#define B_ 4
#define T_ 2048
#define C_ 1024
#define E_ 8
#define H_ 4096
#define NTOK (B_ * T_)     // 8192
#define NPAIR (NTOK * 2)   // 16384
#define BM 128
#define BN 128
#define BK 64              // k-tile (bf16 elements); row = 128 B
#define KSPLIT 2           // phase2 K-split (atomics make this free)
#define MAXTILES 136       // ceil((16384 + 8*127)/128)
#define MAXROWS (MAXTILES * 128)  // 17408
#define NWG1 ((H_ / BN) * MAXTILES)  // 4352 gemm1 blocks

// gemm1_conv appended segments
#define NB_C2 2048   // convert W2
#define NB_CP 1024   // out = x copy (8192 floats/block)

// fused_pre block-range partition
#define NB_C1 2048   // convert W1: (4096/256) x (1024/64) x 8
#define NB_LN NTOK   // 8192
#define NB_CNT (NPAIR / 256)  // 64
#define NB_TID (MAXROWS / 1024)  // 17
#define NB_TOTAL (NB_C1 + NB_LN + NB_CNT + NB_TID)

typedef __bf16 bf16x8 __attribute__((ext_vector_type(8)));
typedef float f32x4 __attribute__((ext_vector_type(4)));
typedef u16 u16x8 __attribute__((ext_vector_type(8)));

__device__ __forceinline__ u16 f2bf(float f) {
    union { float f; u32 u; } c;
    c.f = f;
    u32 r = c.u + 0x7FFFu + ((c.u >> 16) & 1u);  // round-to-nearest-even
    return (u16)(r >> 16);
}

// pack two floats to bf16x2 in a u32 via native RNE casts (compiler can fuse
// to v_cvt_pk_bf16_f32)
__device__ __forceinline__ u32 pk2bf(float a, float b) {
    union { __bf16 h; u16 u; } x, y;
    x.h = (__bf16)a;
    y.h = (__bf16)b;
    return (u32)x.u | ((u32)y.u << 16);
}

// async global->LDS, 16B per lane; LDS dest = wave-uniform base + lane*16
__device__ __forceinline__ void gld16(const void* g, void* l) {
    __builtin_amdgcn_global_load_lds(
        (const __attribute__((address_space(1))) u32*)g,
        (__attribute__((address_space(3))) u32*)l, 16, 0, 0);
}

// ---------------- streaming bodies -------------------------------------------

// LayerNorm: h = bf16(LN(x)). The out=x residual copy lives in gemm1_conv.
__device__ __forceinline__ void ln_body(
    const float* __restrict__ x, const float* __restrict__ gamma,
    const float* __restrict__ beta, u16* __restrict__ h, int token,
    float* smf) {
    const int t = threadIdx.x;
    const float* xr = x + (size_t)token * C_;
    float4 v = *(const float4*)(xr + t * 4);
    float s = v.x + v.y + v.z + v.w;
    float ss = v.x * v.x + v.y * v.y + v.z * v.z + v.w * v.w;
    #pragma unroll
    for (int off = 32; off > 0; off >>= 1) {
        s += __shfl_down(s, off);
        ss += __shfl_down(ss, off);
    }
    float* ws_s = smf;       // [4]
    float* ws_q = smf + 4;   // [4]
    const int wave = t >> 6, lane = t & 63;
    if (lane == 0) { ws_s[wave] = s; ws_q[wave] = ss; }
    __syncthreads();
    float S = ws_s[0] + ws_s[1] + ws_s[2] + ws_s[3];
    float Q = ws_q[0] + ws_q[1] + ws_q[2] + ws_q[3];
    float mu = S * (1.0f / C_);
    float var = Q * (1.0f / C_) - mu * mu;
    float rstd = rsqrtf(var + 1e-5f);
    float4 g = *(const float4*)(gamma + t * 4);
    float4 b = *(const float4*)(beta + t * 4);
    ushort4 hv;
    hv.x = f2bf((v.x - mu) * rstd * g.x + b.x);
    hv.y = f2bf((v.y - mu) * rstd * g.y + b.y);
    hv.z = f2bf((v.z - mu) * rstd * g.z + b.z);
    hv.w = f2bf((v.w - mu) * rstd * g.w + b.w);
    *(ushort4*)(h + (size_t)token * C_ + t * 4) = hv;
}

// Weight convert+transpose fp32 [E][K][N] -> bf16 [E][N][K], streaming tiles
// of 64 k-rows x 256 n-cols (1KB contiguous wave reads, 8x128B row writes,
// conflict-free pitch-258 LDS; u32-packed LDS writes). PERM: src k-row
// permuted per 64-block by phi(r)=((r&3)<<4)|(r>>2) (W2 only).
template <bool PERM>
__device__ __forceinline__ void conv_body(
    const float* __restrict__ in, u16* __restrict__ outp, int K, int N,
    int bid, u16* sm) {
    const int nbx = N >> 8;              // N/256
    const int nby = K >> 6;              // K/64
    const int bx = bid % nbx;
    const int by = (bid / nbx) % nby;
    const int e = bid / (nbx * nby);
    const int k0 = by * 64, n0 = bx * 256;
    const int t = threadIdx.x;
    const float* src = in + (size_t)e * K * N;
    u16* dst = outp + (size_t)e * N * K;
    const int cw = t & 63;        // n-chunk (float4) within row
    const int rw = t >> 6;        // wave index = row offset within pass
    #pragma unroll
    for (int p = 0; p < 16; ++p) {
        const int r = p * 4 + rw;
        const int kr = PERM ? (((r & 3) << 4) | (r >> 2)) : r;
        float4 v = *(const float4*)(src + (size_t)(k0 + kr) * N + n0 + cw * 4);
        const int base = r * 258 + cw * 4;  // u16 idx; byte addr 4-B aligned
        *(u32*)&sm[base + 0] = pk2bf(v.x, v.y);
        *(u32*)&sm[base + 2] = pk2bf(v.z, v.w);
    }
    __syncthreads();
    const u32* smw = (const u32*)sm;
    const int c = t & 7;          // 16B k-chunk within a dst row
    const int ro = t >> 3;        // row-pair offset within pass (0..31)
    #pragma unroll
    for (int p = 0; p < 4; ++p) {
        const int np = p * 32 + ro;          // dst rows 2np, 2np+1
        u16x8 lo, hi;
        #pragma unroll
        for (int m = 0; m < 8; ++m) {
            u32 wv = smw[(c * 8 + m) * 129 + np];
            lo[m] = (u16)(wv & 0xFFFFu);
            hi[m] = (u16)(wv >> 16);
        }
        *(u16x8*)(dst + (size_t)(n0 + 2 * np) * K + k0 + c * 8) = lo;
        *(u16x8*)(dst + (size_t)(n0 + 2 * np + 1) * K + k0 + c * 8) = hi;
    }
}

// Expert count: LDS histogram, per-block slot written NON-atomically.
// counts_arr[b][e] is fully overwritten every run -> no zero-init or memset.
__device__ __forceinline__ void count_body(
    const int* __restrict__ winners, int* __restrict__ counts_arr, int b,
    int* lc) {
    if (threadIdx.x < E_) lc[threadIdx.x] = 0;
    __syncthreads();
    atomicAdd(&lc[winners[b * 256 + threadIdx.x]], 1);  // LDS atomic
    __syncthreads();
    if (threadIdx.x < E_) counts_arr[b * E_ + threadIdx.x] = lc[threadIdx.x];
}

// out = x residual copy: 8192 floats (2048 float4) per block.
__device__ __forceinline__ void copy_body(
    const float* __restrict__ x, float* __restrict__ out, int b) {
    const int t = threadIdx.x;
    const float4* src = (const float4*)x + (size_t)b * 2048;
    float4* dst = (float4*)out + (size_t)b * 2048;
    #pragma unroll
    for (int i = 0; i < 8; ++i) dst[i * 256 + t] = src[i * 256 + t];
}

// ---------------- fused_pre: conv-W1 + LN + count + token_id fill ------------
// Also zeroes pos[] (stream-ordered before place_kernel uses it), removing the
// separate memset dispatch entirely.
__global__ __launch_bounds__(256) void fused_pre(
    const float* __restrict__ x, const float* __restrict__ gamma,
    const float* __restrict__ beta, u16* __restrict__ h,
    const int* __restrict__ winners, int* __restrict__ counts_arr,
    const float* __restrict__ W1, u16* __restrict__ W1T,
    int* __restrict__ token_id, int* __restrict__ pos) {
    __shared__ u16 sm[64 * 258];  // conv buffer; reused by ln (floats) & count
    int b = blockIdx.x;
    if (b < NB_C1) { conv_body<false>(W1, W1T, C_, H_, b, sm); return; }
    b -= NB_C1;
    if (b < NB_LN) { ln_body(x, gamma, beta, h, b, (float*)sm); return; }
    b -= NB_LN;
    if (b < NB_CNT) { count_body(winners, counts_arr, b, (int*)sm); return; }
    b -= NB_CNT;
    if (b == 0 && threadIdx.x < E_) pos[threadIdx.x] = 0;
    const int p = (b * 256 + threadIdx.x) * 4;  // token_id = -1 fill
    if (p < MAXROWS) *(int4*)(token_id + p) = make_int4(-1, -1, -1, -1);
}

// ---------------- Placement: block-aggregated reservation --------------------
// Prologue sums the 64x8 per-block count array (L2-hot) instead of reading a
// single atomically-built counts[]; rest unchanged.
__global__ __launch_bounds__(256) void place_kernel(
    const int* __restrict__ winners, const float* __restrict__ wts,
    const int* __restrict__ counts_arr, int* __restrict__ pos,
    int* __restrict__ token_id, float* __restrict__ pair_w,
    int* __restrict__ tile_expert) {
    __shared__ int po[E_ + 1];
    __shared__ int tot[E_];
    __shared__ int lcount[E_], lbase[E_];
    const int t = threadIdx.x;
    if (t < E_) {
        lcount[t] = 0;
        int c = 0;
        #pragma unroll
        for (int b2 = 0; b2 < NB_CNT; ++b2) c += counts_arr[b2 * E_ + t];
        tot[t] = c;
    }
    __syncthreads();
    if (t == 0) {
        int off = 0;
        po[0] = 0;
        #pragma unroll
        for (int e = 0; e < E_; ++e) {
            off += ((tot[e] + 127) >> 7) << 7;
            po[e + 1] = off;
        }
    }
    __syncthreads();
    if (blockIdx.x == 0 && t < MAXTILES) {
        int r = t * 128;
        int ee = -1;
        if (r < po[E_]) {
            ee = 0;
            while (r >= po[ee + 1]) ++ee;
        }
        tile_expert[t] = ee;
    }
    const int p = blockIdx.x * 256 + t;
    const int e = winners[p];
    const int rank = atomicAdd(&lcount[e], 1);  // LDS atomic
    __syncthreads();
    if (t < E_) {
        int c = lcount[t];
        lbase[t] = c ? atomicAdd(&pos[t], c) : 0;
    }
    __syncthreads();
    const int slot = po[e] + lbase[e] + rank;
    token_id[slot] = p >> 1;
    pair_w[slot] = wts[p];
}

// ---------------- Grouped GEMM body (round-2/4/5 proven, unchanged) ----------
// m97-style async staging + XOR swizzle, 4 blocks/CU implicit wave overlap,
// T1 XCD-bijective swizzle, PHASE2 K-split.
// PHASE2=false: hidden[r,:] = bf16(relu(h[tok(r)] @ W1T[e]^T)^2)  K=1024, N=4096
//               hidden K-dim stored permuted: p64 = lrow*4 + ni
// PHASE2=true : out[tok(r),:] += pair_w[r] * (hidden[r] @ W2T[e]^T) K=4096/KSPLIT
template <bool PHASE2>
__device__ __forceinline__ void gemm_body(
    const u16* __restrict__ Amat, const u16* __restrict__ Bmat,
    const int* __restrict__ token_id, const float* __restrict__ pair_w,
    const int* __restrict__ tile_expert, u16* __restrict__ hidden,
    float* __restrict__ out, const u16* __restrict__ zeropage,
    int bid0, int zi, u16* __restrict__ As, u16* __restrict__ Bs) {
    constexpr int Kdim = PHASE2 ? H_ : C_;            // row pitch of A and B
    constexpr int KRANGE = PHASE2 ? (H_ / KSPLIT) : C_;  // per-block K extent
    constexpr int NWGX = PHASE2 ? (C_ / BN) : (H_ / BN); // 8 or 32
    constexpr int NWG = NWGX * MAXTILES;              // 1088 or 4352 (%8==0)

    int bid = (bid0 & 7) * (NWG >> 3) + (bid0 >> 3);
    const int ct = bid % NWGX;
    const int rt = bid / NWGX;

    const int e = tile_expert[rt];
    if (e < 0) return;
    const int tid = threadIdx.x;
    const int w = tid >> 6;      // wave 0..3
    const int lane = tid & 63;
    const int n0 = ct * BN;
    const int kbase = PHASE2 ? zi * KRANGE : 0;
    const u16* Bb = Bmat + (size_t)e * H_ * C_;

    const int sub = lane >> 3;
    const size_t koffB = (size_t)(((lane & 7) ^ sub) * 16);

    const char* abase[4];
    bool aval[4];
    const char* bbase[4];
    u16* adst[4];
    u16* bdst[4];
    #pragma unroll
    for (int j = 0; j < 4; ++j) {
        const int lrow32 = w * 32 + j * 8 + sub;
        const int grow = rt * BM + lrow32;
        if (PHASE2) {
            aval[j] = true;
            abase[j] = (const char*)(Amat + (size_t)grow * Kdim + kbase) + koffB;
        } else {
            int tok = token_id[grow];
            aval[j] = tok >= 0;
            abase[j] = (const char*)(Amat + (size_t)(tok < 0 ? 0 : tok) * Kdim) + koffB;
        }
        bbase[j] = (const char*)(Bb + (size_t)(n0 + lrow32) * Kdim + kbase) + koffB;
        adst[j] = &As[(w * 32 + j * 8) * BK];
        bdst[j] = &Bs[(w * 32 + j * 8) * BK];
    }

    const int wr = w >> 1, wc = w & 1;
    const int lrow = lane & 15;
    const int quad = lane >> 4;
    const int rsw = lrow & 7;  // read-side swizzle key

    f32x4 acc[4][4] = {};

    for (int k0 = 0; k0 < KRANGE; k0 += BK) {
        __syncthreads();
        const size_t kb = (size_t)k0 * 2;
        #pragma unroll
        for (int j = 0; j < 4; ++j)
            gld16(aval[j] ? abase[j] + kb : (const char*)zeropage, adst[j]);
        #pragma unroll
        for (int j = 0; j < 4; ++j)
            gld16(bbase[j] + kb, bdst[j]);
        __syncthreads();
        #pragma unroll
        for (int kk = 0; kk < 2; ++kk) {
            bf16x8 af[4], bfv[4];
            #pragma unroll
            for (int mi = 0; mi < 4; ++mi) {
                int row = wr * 64 + mi * 16 + lrow;
                int pch = (kk * 4 + quad) ^ rsw;
                af[mi] = *(const bf16x8*)&As[row * BK + pch * 8];
            }
            #pragma unroll
            for (int ni = 0; ni < 4; ++ni) {
                int row = wc * 64 + ni * 16 + lrow;
                int pch = (kk * 4 + quad) ^ rsw;
                bfv[ni] = *(const bf16x8*)&Bs[row * BK + pch * 8];
            }
            #pragma unroll
            for (int mi = 0; mi < 4; ++mi)
                #pragma unroll
                for (int ni = 0; ni < 4; ++ni)
                    acc[mi][ni] = __builtin_amdgcn_mfma_f32_16x16x32_bf16(
                        af[mi], bfv[ni], acc[mi][ni], 0, 0, 0);
        }
    }

    if (!PHASE2) {
        #pragma unroll
        for (int mi = 0; mi < 4; ++mi) {
            int rbase = rt * BM + wr * 64 + mi * 16 + quad * 4;
            #pragma unroll
            for (int j = 0; j < 4; ++j) {
                ushort4 o;
                float v0 = fmaxf(acc[mi][0][j], 0.0f);
                float v1 = fmaxf(acc[mi][1][j], 0.0f);
                float v2 = fmaxf(acc[mi][2][j], 0.0f);
                float v3 = fmaxf(acc[mi][3][j], 0.0f);
                o.x = f2bf(v0 * v0);
                o.y = f2bf(v1 * v1);
                o.z = f2bf(v2 * v2);
                o.w = f2bf(v3 * v3);
                *(ushort4*)&hidden[(size_t)(rbase + j) * H_ + n0 + wc * 64 + lrow * 4] = o;
            }
        }
    } else {
        #pragma unroll
        for (int mi = 0; mi < 4; ++mi) {
            int rbase = rt * BM + wr * 64 + mi * 16 + quad * 4;
            #pragma unroll
            for (int j = 0; j < 4; ++j) {
                int grow = rbase + j;
                int tok = token_id[grow];
                if (tok < 0) continue;
                float pw = pair_w[grow];
                #pragma unroll
                for (int ni = 0; ni < 4; ++ni) {
                    int col = n0 + wc * 64 + ni * 16 + lrow;
                    atomicAdd(&out[(size_t)tok * C_ + col], pw * acc[mi][ni][j]);
                }
            }
        }
    }
}

// ---------------- gemm1 + conv-W2 + out=x soak (horizontal fusion) -----------
// conv-W2 and the residual copy only gate gemm2; gemm1 uses ~16% of HBM BW,
// so their ~256 MB streams free under gemm1's compute. LDS union 33 KB.
__global__ __launch_bounds__(256, 4) void gemm1_conv(
    const u16* __restrict__ h, const u16* __restrict__ W1T,
    const int* __restrict__ token_id, const float* __restrict__ pair_w,
    const int* __restrict__ tile_expert, u16* __restrict__ hidden,
    const u16* __restrict__ zeropage, const float* __restrict__ W2,
    u16* __restrict__ W2T, const float* __restrict__ x,
    float* __restrict__ out) {
    __shared__ u16 smu[64 * 258];  // 33 KB union: gemm uses first 32 KB
    const int b = blockIdx.x;
    if (b < NWG1) {
        gemm_body<false>(h, W1T, token_id, pair_w, tile_expert, hidden,
                         nullptr, zeropage, b, 0, smu, smu + BM * BK);
    } else if (b < NWG1 + NB_C2) {
        conv_body<true>(W2, W2T, H_, C_, b - NWG1, smu);
    } else {
        copy_body(x, out, b - NWG1 - NB_C2);
    }
}

// ---------------- phase2 wrapper: LB(256,4) — 5/CU spills (R10 post-mortem:
// acc alone needs 64 VGPR; 5 waves/SIMD caps ~102 total -> scratch, 2.2x) ----
__global__ __launch_bounds__(256, 4) void gemm2_kernel(
    const u16* __restrict__ hidden, const u16* __restrict__ W2T,
    const int* __restrict__ token_id, const float* __restrict__ pair_w,
    const int* __restrict__ tile_expert, float* __restrict__ out,
    const u16* __restrict__ zeropage) {
    __shared__ u16 As[BM * BK];
    __shared__ u16 Bs[BN * BK];
    const int bid = blockIdx.y * (C_ / BN) + blockIdx.x;
    gemm_body<true>(hidden, W2T, token_id, pair_w, tile_expert, nullptr, out,
                    zeropage, bid, blockIdx.z, As, Bs);
}

// ---------------- Launch ----------------
extern "C" void kernel_launch(void* const* d_in, const int* in_sizes, int n_in,
                              void* d_out, int out_size, void* d_ws, size_t ws_size,
                              hipStream_t stream) {
    const float* x = (const float*)d_in[0];
    const float* weights = (const float*)d_in[1];
    const float* gamma = (const float*)d_in[2];
    const float* beta = (const float*)d_in[3];
    const float* W1 = (const float*)d_in[4];
    const float* W2 = (const float*)d_in[5];
    const int* winners = (const int*)d_in[6];
    float* out = (float*)d_out;

    char* ws = (char*)d_ws;
    const size_t SZ_H = (size_t)NTOK * C_ * 2;           // 16 MB
    const size_t SZ_HID = (size_t)MAXROWS * H_ * 2;      // 136 MB
    const size_t SZ_WT = (size_t)E_ * H_ * C_ * 2;       // 64 MB each
    const size_t OFF_HID = SZ_H;
    const size_t OFF_W1T = OFF_HID + SZ_HID;
    const size_t OFF_W2T = OFF_W1T + SZ_WT;
    const size_t OFF_META = OFF_W2T + SZ_WT;

    u16* h = (u16*)ws;
    u16* hidden = (u16*)(ws + OFF_HID);
    u16* W1T = (u16*)(ws + OFF_W1T);
    u16* W2T = (u16*)(ws + OFF_W2T);
    int* meta = (int*)(ws + OFF_META);
    int* pos = meta + 8;                // [8,16)
    u16* zeropage = (u16*)(meta + 32);  // [32,48) 64 B region, 16B-aligned
                                        // (contents row-isolated -> no zeroing)
    int* tile_expert = meta + 48;       // [48,184), fully rewritten each run
    int* counts_arr = meta + 192;       // [192,704): 64 blocks x 8 experts
    int* token_id = meta + 704;         // 16B-aligned (704*4 = 2816)
    float* pair_w = (float*)(meta + 704 + MAXROWS);

    fused_pre<<<NB_TOTAL, 256, 0, stream>>>(x, gamma, beta, h, winners,
                                            counts_arr, W1, W1T, token_id, pos);
    place_kernel<<<NPAIR / 256, 256, 0, stream>>>(winners, weights, counts_arr,
                                                  pos, token_id, pair_w,
                                                  tile_expert);
    gemm1_conv<<<NWG1 + NB_C2 + NB_CP, 256, 0, stream>>>(
        h, W1T, token_id, pair_w, tile_expert, hidden, zeropage, W2, W2T, x, out);
    gemm2_kernel<<<dim3(C_ / BN, MAXTILES, KSPLIT), 256, 0, stream>>>(
        hidden, W2T, token_id, pair_w, tile_expert, out, zeropage);
}

// Round 12
// 682.397 us; speedup vs baseline: 1.4031x; 1.0289x over previous
//
#include <hip/hip_runtime.h>
#include <stddef.h>

typedef unsigned short u16;
typedef unsigned int u32;

#define B_ 4
#define T_ 2048
#define C_ 1024
#define E_ 8
#define H_ 4096
#define NTOK (B_ * T_)     // 8192
#define NPAIR (NTOK * 2)   // 16384
#define BM 128
#define BN 128
#define BK 64              // k-tile (bf16 elements); row = 128 B
#define KSPLIT 2           // phase2 K-split (atomics make this free)
#define MAXTILES 136       // ceil((16384 + 8*127)/128)
#define MAXROWS (MAXTILES * 128)  // 17408
#define NWG1 ((H_ / BN) * MAXTILES)  // 4352 gemm1 blocks

// gemm1_conv appended segments
#define NB_C2 4096   // convert W2: (1024/128) x (4096/64) x 8
#define NB_CP 1024   // out = x copy (8192 floats/block)

// fused_pre block-range partition
#define NB_C1 4096   // convert W1: (4096/128) x (1024/64) x 8
#define NB_LN NTOK   // 8192
#define NB_CNT (NPAIR / 256)  // 64
#define NB_TID (MAXROWS / 1024)  // 17
#define NB_TOTAL (NB_C1 + NB_LN + NB_CNT + NB_TID)

typedef __bf16 bf16x8 __attribute__((ext_vector_type(8)));
typedef float f32x4 __attribute__((ext_vector_type(4)));
typedef u16 u16x8 __attribute__((ext_vector_type(8)));

__device__ __forceinline__ u16 f2bf(float f) {
    union { float f; u32 u; } c;
    c.f = f;
    u32 r = c.u + 0x7FFFu + ((c.u >> 16) & 1u);  // round-to-nearest-even
    return (u16)(r >> 16);
}

// pack two floats to bf16x2 in a u32 via native RNE casts (compiler can fuse
// to v_cvt_pk_bf16_f32)
__device__ __forceinline__ u32 pk2bf(float a, float b) {
    union { __bf16 h; u16 u; } x, y;
    x.h = (__bf16)a;
    y.h = (__bf16)b;
    return (u32)x.u | ((u32)y.u << 16);
}

// async global->LDS, 16B per lane; LDS dest = wave-uniform base + lane*16
__device__ __forceinline__ void gld16(const void* g, void* l) {
    __builtin_amdgcn_global_load_lds(
        (const __attribute__((address_space(1))) u32*)g,
        (__attribute__((address_space(3))) u32*)l, 16, 0, 0);
}

// ---------------- streaming bodies -------------------------------------------

// LayerNorm: h = bf16(LN(x)). The out=x residual copy lives in gemm1_conv.
__device__ __forceinline__ void ln_body(
    const float* __restrict__ x, const float* __restrict__ gamma,
    const float* __restrict__ beta, u16* __restrict__ h, int token,
    float* smf) {
    const int t = threadIdx.x;
    const float* xr = x + (size_t)token * C_;
    float4 v = *(const float4*)(xr + t * 4);
    float s = v.x + v.y + v.z + v.w;
    float ss = v.x * v.x + v.y * v.y + v.z * v.z + v.w * v.w;
    #pragma unroll
    for (int off = 32; off > 0; off >>= 1) {
        s += __shfl_down(s, off);
        ss += __shfl_down(ss, off);
    }
    float* ws_s = smf;       // [4]
    float* ws_q = smf + 4;   // [4]
    const int wave = t >> 6, lane = t & 63;
    if (lane == 0) { ws_s[wave] = s; ws_q[wave] = ss; }
    __syncthreads();
    float S = ws_s[0] + ws_s[1] + ws_s[2] + ws_s[3];
    float Q = ws_q[0] + ws_q[1] + ws_q[2] + ws_q[3];
    float mu = S * (1.0f / C_);
    float var = Q * (1.0f / C_) - mu * mu;
    float rstd = rsqrtf(var + 1e-5f);
    float4 g = *(const float4*)(gamma + t * 4);
    float4 b = *(const float4*)(beta + t * 4);
    ushort4 hv;
    hv.x = f2bf((v.x - mu) * rstd * g.x + b.x);
    hv.y = f2bf((v.y - mu) * rstd * g.y + b.y);
    hv.z = f2bf((v.z - mu) * rstd * g.z + b.z);
    hv.w = f2bf((v.w - mu) * rstd * g.w + b.w);
    *(ushort4*)(h + (size_t)token * C_ + t * 4) = hv;
}

// Weight convert+transpose fp32 [E][K][N] -> bf16 [E][N][K].
// Tile = 64 k-rows x 128 n-cols: LDS 16.6 KB (pitch-130 u16) -> 8-9 blocks/CU
// (was 33 KB / 4 blocks/CU -- fused_pre was overlap-bound, not BW-bound).
// Reads: 512 B contiguous per wave-instr; writes: 128 B per dst row (full
// 64-k extent), conflict-free by mod-32 analysis (same structure as pitch-258).
// PERM: src k-row permuted per 64-block by phi(r)=((r&3)<<4)|(r>>2) (W2 only).
template <bool PERM>
__device__ __forceinline__ void conv_body(
    const float* __restrict__ in, u16* __restrict__ outp, int K, int N,
    int bid, u16* sm) {
    const int nbx = N >> 7;              // N/128
    const int nby = K >> 6;              // K/64
    const int bx = bid % nbx;
    const int by = (bid / nbx) % nby;
    const int e = bid / (nbx * nby);
    const int k0 = by * 64, n0 = bx * 128;
    const int t = threadIdx.x;
    const float* src = in + (size_t)e * K * N;
    u16* dst = outp + (size_t)e * N * K;
    const int cw = t & 31;        // n-chunk (float4) within row (32 x 16 B)
    const int rw = t >> 5;        // 0..7: row offset within pass
    #pragma unroll
    for (int p = 0; p < 8; ++p) {
        const int r = p * 8 + rw;
        const int kr = PERM ? (((r & 3) << 4) | (r >> 2)) : r;
        float4 v = *(const float4*)(src + (size_t)(k0 + kr) * N + n0 + cw * 4);
        const int base = r * 130 + cw * 4;  // u16 idx; byte addr 4-B aligned
        *(u32*)&sm[base + 0] = pk2bf(v.x, v.y);
        *(u32*)&sm[base + 2] = pk2bf(v.z, v.w);
    }
    __syncthreads();
    const u32* smw = (const u32*)sm;  // pitch 65 u32
    const int c = t & 7;          // 16B k-chunk within a dst row
    const int ro = t >> 3;        // row-pair offset (0..31)
    #pragma unroll
    for (int p = 0; p < 2; ++p) {
        const int np = p * 32 + ro;          // dst rows 2np, 2np+1 (0..127)
        u16x8 lo, hi;
        #pragma unroll
        for (int m = 0; m < 8; ++m) {
            u32 wv = smw[(c * 8 + m) * 65 + np];  // {sm[k][2np], sm[k][2np+1]}
            lo[m] = (u16)(wv & 0xFFFFu);
            hi[m] = (u16)(wv >> 16);
        }
        *(u16x8*)(dst + (size_t)(n0 + 2 * np) * K + k0 + c * 8) = lo;
        *(u16x8*)(dst + (size_t)(n0 + 2 * np + 1) * K + k0 + c * 8) = hi;
    }
}

// Expert count: LDS histogram, per-block slot written NON-atomically.
// counts_arr[b][e] is fully overwritten every run -> no zero-init or memset.
__device__ __forceinline__ void count_body(
    const int* __restrict__ winners, int* __restrict__ counts_arr, int b,
    int* lc) {
    if (threadIdx.x < E_) lc[threadIdx.x] = 0;
    __syncthreads();
    atomicAdd(&lc[winners[b * 256 + threadIdx.x]], 1);  // LDS atomic
    __syncthreads();
    if (threadIdx.x < E_) counts_arr[b * E_ + threadIdx.x] = lc[threadIdx.x];
}

// out = x residual copy: 8192 floats (2048 float4) per block.
__device__ __forceinline__ void copy_body(
    const float* __restrict__ x, float* __restrict__ out, int b) {
    const int t = threadIdx.x;
    const float4* src = (const float4*)x + (size_t)b * 2048;
    float4* dst = (float4*)out + (size_t)b * 2048;
    #pragma unroll
    for (int i = 0; i < 8; ++i) dst[i * 256 + t] = src[i * 256 + t];
}

// ---------------- fused_pre: conv-W1 + LN + count + token_id fill ------------
// Shared = 16.6 KB (conv tile) -> 8-9 blocks/CU for every segment.
// Also zeroes pos[] (stream-ordered before place_kernel).
__global__ __launch_bounds__(256) void fused_pre(
    const float* __restrict__ x, const float* __restrict__ gamma,
    const float* __restrict__ beta, u16* __restrict__ h,
    const int* __restrict__ winners, int* __restrict__ counts_arr,
    const float* __restrict__ W1, u16* __restrict__ W1T,
    int* __restrict__ token_id, int* __restrict__ pos) {
    __shared__ u16 sm[64 * 130];  // 16.6 KB; reused by ln (floats) & count
    int b = blockIdx.x;
    if (b < NB_C1) { conv_body<false>(W1, W1T, C_, H_, b, sm); return; }
    b -= NB_C1;
    if (b < NB_LN) { ln_body(x, gamma, beta, h, b, (float*)sm); return; }
    b -= NB_LN;
    if (b < NB_CNT) { count_body(winners, counts_arr, b, (int*)sm); return; }
    b -= NB_CNT;
    if (b == 0 && threadIdx.x < E_) pos[threadIdx.x] = 0;
    const int p = (b * 256 + threadIdx.x) * 4;  // token_id = -1 fill
    if (p < MAXROWS) *(int4*)(token_id + p) = make_int4(-1, -1, -1, -1);
}

// ---------------- Placement: block-aggregated reservation --------------------
__global__ __launch_bounds__(256) void place_kernel(
    const int* __restrict__ winners, const float* __restrict__ wts,
    const int* __restrict__ counts_arr, int* __restrict__ pos,
    int* __restrict__ token_id, float* __restrict__ pair_w,
    int* __restrict__ tile_expert) {
    __shared__ int po[E_ + 1];
    __shared__ int tot[E_];
    __shared__ int lcount[E_], lbase[E_];
    const int t = threadIdx.x;
    if (t < E_) {
        lcount[t] = 0;
        int c = 0;
        #pragma unroll
        for (int b2 = 0; b2 < NB_CNT; ++b2) c += counts_arr[b2 * E_ + t];
        tot[t] = c;
    }
    __syncthreads();
    if (t == 0) {
        int off = 0;
        po[0] = 0;
        #pragma unroll
        for (int e = 0; e < E_; ++e) {
            off += ((tot[e] + 127) >> 7) << 7;
            po[e + 1] = off;
        }
    }
    __syncthreads();
    if (blockIdx.x == 0 && t < MAXTILES) {
        int r = t * 128;
        int ee = -1;
        if (r < po[E_]) {
            ee = 0;
            while (r >= po[ee + 1]) ++ee;
        }
        tile_expert[t] = ee;
    }
    const int p = blockIdx.x * 256 + t;
    const int e = winners[p];
    const int rank = atomicAdd(&lcount[e], 1);  // LDS atomic
    __syncthreads();
    if (t < E_) {
        int c = lcount[t];
        lbase[t] = c ? atomicAdd(&pos[t], c) : 0;
    }
    __syncthreads();
    const int slot = po[e] + lbase[e] + rank;
    token_id[slot] = p >> 1;
    pair_w[slot] = wts[p];
}

// ---------------- Grouped GEMM body (round-2/4/5 proven, unchanged) ----------
// m97-style async staging + XOR swizzle, 4 blocks/CU implicit wave overlap,
// T1 XCD-bijective swizzle, PHASE2 K-split.
// PHASE2=false: hidden[r,:] = bf16(relu(h[tok(r)] @ W1T[e]^T)^2)  K=1024, N=4096
//               hidden K-dim stored permuted: p64 = lrow*4 + ni
// PHASE2=true : out[tok(r),:] += pair_w[r] * (hidden[r] @ W2T[e]^T) K=4096/KSPLIT
template <bool PHASE2>
__device__ __forceinline__ void gemm_body(
    const u16* __restrict__ Amat, const u16* __restrict__ Bmat,
    const int* __restrict__ token_id, const float* __restrict__ pair_w,
    const int* __restrict__ tile_expert, u16* __restrict__ hidden,
    float* __restrict__ out, const u16* __restrict__ zeropage,
    int bid0, int zi, u16* __restrict__ As, u16* __restrict__ Bs) {
    constexpr int Kdim = PHASE2 ? H_ : C_;            // row pitch of A and B
    constexpr int KRANGE = PHASE2 ? (H_ / KSPLIT) : C_;  // per-block K extent
    constexpr int NWGX = PHASE2 ? (C_ / BN) : (H_ / BN); // 8 or 32
    constexpr int NWG = NWGX * MAXTILES;              // 1088 or 4352 (%8==0)

    int bid = (bid0 & 7) * (NWG >> 3) + (bid0 >> 3);
    const int ct = bid % NWGX;
    const int rt = bid / NWGX;

    const int e = tile_expert[rt];
    if (e < 0) return;
    const int tid = threadIdx.x;
    const int w = tid >> 6;      // wave 0..3
    const int lane = tid & 63;
    const int n0 = ct * BN;
    const int kbase = PHASE2 ? zi * KRANGE : 0;
    const u16* Bb = Bmat + (size_t)e * H_ * C_;

    const int sub = lane >> 3;
    const size_t koffB = (size_t)(((lane & 7) ^ sub) * 16);

    const char* abase[4];
    bool aval[4];
    const char* bbase[4];
    u16* adst[4];
    u16* bdst[4];
    #pragma unroll
    for (int j = 0; j < 4; ++j) {
        const int lrow32 = w * 32 + j * 8 + sub;
        const int grow = rt * BM + lrow32;
        if (PHASE2) {
            aval[j] = true;
            abase[j] = (const char*)(Amat + (size_t)grow * Kdim + kbase) + koffB;
        } else {
            int tok = token_id[grow];
            aval[j] = tok >= 0;
            abase[j] = (const char*)(Amat + (size_t)(tok < 0 ? 0 : tok) * Kdim) + koffB;
        }
        bbase[j] = (const char*)(Bb + (size_t)(n0 + lrow32) * Kdim + kbase) + koffB;
        adst[j] = &As[(w * 32 + j * 8) * BK];
        bdst[j] = &Bs[(w * 32 + j * 8) * BK];
    }

    const int wr = w >> 1, wc = w & 1;
    const int lrow = lane & 15;
    const int quad = lane >> 4;
    const int rsw = lrow & 7;  // read-side swizzle key

    f32x4 acc[4][4] = {};

    for (int k0 = 0; k0 < KRANGE; k0 += BK) {
        __syncthreads();
        const size_t kb = (size_t)k0 * 2;
        #pragma unroll
        for (int j = 0; j < 4; ++j)
            gld16(aval[j] ? abase[j] + kb : (const char*)zeropage, adst[j]);
        #pragma unroll
        for (int j = 0; j < 4; ++j)
            gld16(bbase[j] + kb, bdst[j]);
        __syncthreads();
        #pragma unroll
        for (int kk = 0; kk < 2; ++kk) {
            bf16x8 af[4], bfv[4];
            #pragma unroll
            for (int mi = 0; mi < 4; ++mi) {
                int row = wr * 64 + mi * 16 + lrow;
                int pch = (kk * 4 + quad) ^ rsw;
                af[mi] = *(const bf16x8*)&As[row * BK + pch * 8];
            }
            #pragma unroll
            for (int ni = 0; ni < 4; ++ni) {
                int row = wc * 64 + ni * 16 + lrow;
                int pch = (kk * 4 + quad) ^ rsw;
                bfv[ni] = *(const bf16x8*)&Bs[row * BK + pch * 8];
            }
            #pragma unroll
            for (int mi = 0; mi < 4; ++mi)
                #pragma unroll
                for (int ni = 0; ni < 4; ++ni)
                    acc[mi][ni] = __builtin_amdgcn_mfma_f32_16x16x32_bf16(
                        af[mi], bfv[ni], acc[mi][ni], 0, 0, 0);
        }
    }

    if (!PHASE2) {
        #pragma unroll
        for (int mi = 0; mi < 4; ++mi) {
            int rbase = rt * BM + wr * 64 + mi * 16 + quad * 4;
            #pragma unroll
            for (int j = 0; j < 4; ++j) {
                ushort4 o;
                float v0 = fmaxf(acc[mi][0][j], 0.0f);
                float v1 = fmaxf(acc[mi][1][j], 0.0f);
                float v2 = fmaxf(acc[mi][2][j], 0.0f);
                float v3 = fmaxf(acc[mi][3][j], 0.0f);
                o.x = f2bf(v0 * v0);
                o.y = f2bf(v1 * v1);
                o.z = f2bf(v2 * v2);
                o.w = f2bf(v3 * v3);
                *(ushort4*)&hidden[(size_t)(rbase + j) * H_ + n0 + wc * 64 + lrow * 4] = o;
            }
        }
    } else {
        #pragma unroll
        for (int mi = 0; mi < 4; ++mi) {
            int rbase = rt * BM + wr * 64 + mi * 16 + quad * 4;
            #pragma unroll
            for (int j = 0; j < 4; ++j) {
                int grow = rbase + j;
                int tok = token_id[grow];
                if (tok < 0) continue;
                float pw = pair_w[grow];
                #pragma unroll
                for (int ni = 0; ni < 4; ++ni) {
                    int col = n0 + wc * 64 + ni * 16 + lrow;
                    atomicAdd(&out[(size_t)tok * C_ + col], pw * acc[mi][ni][j]);
                }
            }
        }
    }
}

// ---------------- gemm1 + conv-W2 + out=x soak (horizontal fusion) -----------
// conv-W2 and the residual copy only gate gemm2; gemm1 uses ~16% of HBM BW,
// so their ~256 MB streams free under gemm1's compute. LDS union = 32 KB.
__global__ __launch_bounds__(256, 4) void gemm1_conv(
    const u16* __restrict__ h, const u16* __restrict__ W1T,
    const int* __restrict__ token_id, const float* __restrict__ pair_w,
    const int* __restrict__ tile_expert, u16* __restrict__ hidden,
    const u16* __restrict__ zeropage, const float* __restrict__ W2,
    u16* __restrict__ W2T, const float* __restrict__ x,
    float* __restrict__ out) {
    __shared__ u16 smu[2 * BM * BK];  // 32 KB: gemm As+Bs; conv uses 16.6 KB
    const int b = blockIdx.x;
    if (b < NWG1) {
        gemm_body<false>(h, W1T, token_id, pair_w, tile_expert, hidden,
                         nullptr, zeropage, b, 0, smu, smu + BM * BK);
    } else if (b < NWG1 + NB_C2) {
        conv_body<true>(W2, W2T, H_, C_, b - NWG1, smu);
    } else {
        copy_body(x, out, b - NWG1 - NB_C2);
    }
}

// ---------------- phase2 wrapper: LB(256,4) — 5/CU spills (R10 post-mortem:
// acc alone needs 64 VGPR; 5 waves/SIMD caps ~102 total -> scratch, 2.2x) ----
__global__ __launch_bounds__(256, 4) void gemm2_kernel(
    const u16* __restrict__ hidden, const u16* __restrict__ W2T,
    const int* __restrict__ token_id, const float* __restrict__ pair_w,
    const int* __restrict__ tile_expert, float* __restrict__ out,
    const u16* __restrict__ zeropage) {
    __shared__ u16 As[BM * BK];
    __shared__ u16 Bs[BN * BK];
    const int bid = blockIdx.y * (C_ / BN) + blockIdx.x;
    gemm_body<true>(hidden, W2T, token_id, pair_w, tile_expert, nullptr, out,
                    zeropage, bid, blockIdx.z, As, Bs);
}

// ---------------- Launch ----------------
extern "C" void kernel_launch(void* const* d_in, const int* in_sizes, int n_in,
                              void* d_out, int out_size, void* d_ws, size_t ws_size,
                              hipStream_t stream) {
    const float* x = (const float*)d_in[0];
    const float* weights = (const float*)d_in[1];
    const float* gamma = (const float*)d_in[2];
    const float* beta = (const float*)d_in[3];
    const float* W1 = (const float*)d_in[4];
    const float* W2 = (const float*)d_in[5];
    const int* winners = (const int*)d_in[6];
    float* out = (float*)d_out;

    char* ws = (char*)d_ws;
    const size_t SZ_H = (size_t)NTOK * C_ * 2;           // 16 MB
    const size_t SZ_HID = (size_t)MAXROWS * H_ * 2;      // 136 MB
    const size_t SZ_WT = (size_t)E_ * H_ * C_ * 2;       // 64 MB each
    const size_t OFF_HID = SZ_H;
    const size_t OFF_W1T = OFF_HID + SZ_HID;
    const size_t OFF_W2T = OFF_W1T + SZ_WT;
    const size_t OFF_META = OFF_W2T + SZ_WT;

    u16* h = (u16*)ws;
    u16* hidden = (u16*)(ws + OFF_HID);
    u16* W1T = (u16*)(ws + OFF_W1T);
    u16* W2T = (u16*)(ws + OFF_W2T);
    int* meta = (int*)(ws + OFF_META);
    int* pos = meta + 8;                // [8,16)
    u16* zeropage = (u16*)(meta + 32);  // [32,48) 64 B region, 16B-aligned
                                        // (contents row-isolated -> no zeroing)
    int* tile_expert = meta + 48;       // [48,184), fully rewritten each run
    int* counts_arr = meta + 192;       // [192,704): 64 blocks x 8 experts
    int* token_id = meta + 704;         // 16B-aligned (704*4 = 2816)
    float* pair_w = (float*)(meta + 704 + MAXROWS);

    fused_pre<<<NB_TOTAL, 256, 0, stream>>>(x, gamma, beta, h, winners,
                                            counts_arr, W1, W1T, token_id, pos);
    place_kernel<<<NPAIR / 256, 256, 0, stream>>>(winners, weights, counts_arr,
                                                  pos, token_id, pair_w,
                                                  tile_expert);
    gemm1_conv<<<NWG1 + NB_C2 + NB_CP, 256, 0, stream>>>(
        h, W1T, token_id, pair_w, tile_expert, hidden, zeropage, W2, W2T, x, out);
    gemm2_kernel<<<dim3(C_ / BN, MAXTILES, KSPLIT), 256, 0, stream>>>(
        hidden, W2T, token_id, pair_w, tile_expert, out, zeropage);
}

// Round 14
// 674.561 us; speedup vs baseline: 1.4194x; 1.0116x over previous
//
#include <hip/hip_runtime.h>
#include <stddef.h>

typedef unsigned short u16;
typedef unsigned int u32;

#define B_ 4
#define T_ 2048
#define C_ 1024
#define E_ 8
#define H_ 4096
#define NTOK (B_ * T_)     // 8192
#define NPAIR (NTOK * 2)   // 16384
#define BM 128
#define BN 128
#define BK 64              // k-tile (bf16 elements); row = 128 B
#define KSPLIT 2           // phase2 K-split (atomics make this free)
#define MAXTILES 136       // ceil((16384 + 8*127)/128)
#define MAXROWS (MAXTILES * 128)  // 17408
#define NWG1 ((H_ / BN) * MAXTILES)  // 4352 gemm1 blocks

// gemm1_conv appended segments
#define NB_C2 4096   // convert W2: (1024/128) x (4096/64) x 8
#define NB_CP 1024   // out = x copy (8192 floats/block)

// fused_pre block-range partition
#define NB_C1 4096   // convert W1: (4096/128) x (1024/64) x 8
#define NB_LN NTOK   // 8192
#define NB_CNT (NPAIR / 256)  // 64
#define NB_TID (MAXROWS / 1024)  // 17
#define NB_TOTAL (NB_C1 + NB_LN + NB_CNT + NB_TID)

typedef __bf16 bf16x8 __attribute__((ext_vector_type(8)));
typedef float f32x4 __attribute__((ext_vector_type(4)));
typedef u16 u16x8 __attribute__((ext_vector_type(8)));
typedef u16 u16x4 __attribute__((ext_vector_type(4)));

__device__ __forceinline__ u16 f2bf(float f) {
    union { float f; u32 u; } c;
    c.f = f;
    u32 r = c.u + 0x7FFFu + ((c.u >> 16) & 1u);  // round-to-nearest-even
    return (u16)(r >> 16);
}

// pack two floats to bf16x2 in a u32 via native RNE casts (compiler can fuse
// to v_cvt_pk_bf16_f32)
__device__ __forceinline__ u32 pk2bf(float a, float b) {
    union { __bf16 h; u16 u; } x, y;
    x.h = (__bf16)a;
    y.h = (__bf16)b;
    return (u32)x.u | ((u32)y.u << 16);
}

// async global->LDS, 16B per lane; LDS dest = wave-uniform base + lane*16
__device__ __forceinline__ void gld16(const void* g, void* l) {
    __builtin_amdgcn_global_load_lds(
        (const __attribute__((address_space(1))) u32*)g,
        (__attribute__((address_space(3))) u32*)l, 16, 0, 0);
}

// ---------------- streaming bodies -------------------------------------------

// LayerNorm: h = bf16(LN(x)). The out=x residual copy lives in gemm1_conv.
__device__ __forceinline__ void ln_body(
    const float* __restrict__ x, const float* __restrict__ gamma,
    const float* __restrict__ beta, u16* __restrict__ h, int token,
    float* smf) {
    const int t = threadIdx.x;
    const float* xr = x + (size_t)token * C_;
    float4 v = *(const float4*)(xr + t * 4);
    float s = v.x + v.y + v.z + v.w;
    float ss = v.x * v.x + v.y * v.y + v.z * v.z + v.w * v.w;
    #pragma unroll
    for (int off = 32; off > 0; off >>= 1) {
        s += __shfl_down(s, off);
        ss += __shfl_down(ss, off);
    }
    float* ws_s = smf;       // [4]
    float* ws_q = smf + 4;   // [4]
    const int wave = t >> 6, lane = t & 63;
    if (lane == 0) { ws_s[wave] = s; ws_q[wave] = ss; }
    __syncthreads();
    float S = ws_s[0] + ws_s[1] + ws_s[2] + ws_s[3];
    float Q = ws_q[0] + ws_q[1] + ws_q[2] + ws_q[3];
    float mu = S * (1.0f / C_);
    float var = Q * (1.0f / C_) - mu * mu;
    float rstd = rsqrtf(var + 1e-5f);
    float4 g = *(const float4*)(gamma + t * 4);
    float4 b = *(const float4*)(beta + t * 4);
    ushort4 hv;
    hv.x = f2bf((v.x - mu) * rstd * g.x + b.x);
    hv.y = f2bf((v.y - mu) * rstd * g.y + b.y);
    hv.z = f2bf((v.z - mu) * rstd * g.z + b.z);
    hv.w = f2bf((v.w - mu) * rstd * g.w + b.w);
    *(ushort4*)(h + (size_t)token * C_ + t * 4) = hv;
}

// Weight convert+transpose fp32 [E][K][N] -> bf16 [E][N][K].
// Tile = 64 k-rows x 128 n-cols, LDS 16.6 KB (pitch-130 u16), 8-9 blocks/CU.
// Dst stores are NON-TEMPORAL: W1T/W2T are consumed much later (by the gemms)
// and streaming them through L2 only evicts concurrently-useful lines.
// PERM: src k-row permuted per 64-block by phi(r)=((r&3)<<4)|(r>>2) (W2 only).
template <bool PERM>
__device__ __forceinline__ void conv_body(
    const float* __restrict__ in, u16* __restrict__ outp, int K, int N,
    int bid, u16* sm) {
    const int nbx = N >> 7;              // N/128
    const int nby = K >> 6;              // K/64
    const int bx = bid % nbx;
    const int by = (bid / nbx) % nby;
    const int e = bid / (nbx * nby);
    const int k0 = by * 64, n0 = bx * 128;
    const int t = threadIdx.x;
    const float* src = in + (size_t)e * K * N;
    u16* dst = outp + (size_t)e * N * K;
    const int cw = t & 31;        // n-chunk (float4) within row (32 x 16 B)
    const int rw = t >> 5;        // 0..7: row offset within pass
    #pragma unroll
    for (int p = 0; p < 8; ++p) {
        const int r = p * 8 + rw;
        const int kr = PERM ? (((r & 3) << 4) | (r >> 2)) : r;
        float4 v = *(const float4*)(src + (size_t)(k0 + kr) * N + n0 + cw * 4);
        const int base = r * 130 + cw * 4;  // u16 idx; byte addr 4-B aligned
        *(u32*)&sm[base + 0] = pk2bf(v.x, v.y);
        *(u32*)&sm[base + 2] = pk2bf(v.z, v.w);
    }
    __syncthreads();
    const u32* smw = (const u32*)sm;  // pitch 65 u32
    const int c = t & 7;          // 16B k-chunk within a dst row
    const int ro = t >> 3;        // row-pair offset (0..31)
    #pragma unroll
    for (int p = 0; p < 2; ++p) {
        const int np = p * 32 + ro;          // dst rows 2np, 2np+1 (0..127)
        u16x8 lo, hi;
        #pragma unroll
        for (int m = 0; m < 8; ++m) {
            u32 wv = smw[(c * 8 + m) * 65 + np];  // {sm[k][2np], sm[k][2np+1]}
            lo[m] = (u16)(wv & 0xFFFFu);
            hi[m] = (u16)(wv >> 16);
        }
        __builtin_nontemporal_store(
            lo, (u16x8*)(dst + (size_t)(n0 + 2 * np) * K + k0 + c * 8));
        __builtin_nontemporal_store(
            hi, (u16x8*)(dst + (size_t)(n0 + 2 * np + 1) * K + k0 + c * 8));
    }
}

// Expert count: LDS histogram, per-block slot written NON-atomically.
// counts_arr[b][e] is fully overwritten every run -> no zero-init or memset.
__device__ __forceinline__ void count_body(
    const int* __restrict__ winners, int* __restrict__ counts_arr, int b,
    int* lc) {
    if (threadIdx.x < E_) lc[threadIdx.x] = 0;
    __syncthreads();
    atomicAdd(&lc[winners[b * 256 + threadIdx.x]], 1);  // LDS atomic
    __syncthreads();
    if (threadIdx.x < E_) counts_arr[b * E_ + threadIdx.x] = lc[threadIdx.x];
}

// out = x residual copy: 8192 floats (2048 f32x4) per block. NT stores: out
// is only touched again by gemm2's atomics, long after L2 residency expires.
__device__ __forceinline__ void copy_body(
    const float* __restrict__ x, float* __restrict__ out, int b) {
    const int t = threadIdx.x;
    const f32x4* src = (const f32x4*)x + (size_t)b * 2048;
    f32x4* dst = (f32x4*)out + (size_t)b * 2048;
    #pragma unroll
    for (int i = 0; i < 8; ++i) {
        f32x4 v = src[i * 256 + t];
        __builtin_nontemporal_store(v, dst + i * 256 + t);
    }
}

// ---------------- fused_pre: conv-W1 + LN + count + token_id fill ------------
// Shared = 16.6 KB (conv tile) -> 8-9 blocks/CU for every segment.
// Also zeroes pos[] (stream-ordered before place_kernel).
__global__ __launch_bounds__(256) void fused_pre(
    const float* __restrict__ x, const float* __restrict__ gamma,
    const float* __restrict__ beta, u16* __restrict__ h,
    const int* __restrict__ winners, int* __restrict__ counts_arr,
    const float* __restrict__ W1, u16* __restrict__ W1T,
    int* __restrict__ token_id, int* __restrict__ pos) {
    __shared__ u16 sm[64 * 130];  // 16.6 KB; reused by ln (floats) & count
    int b = blockIdx.x;
    if (b < NB_C1) { conv_body<false>(W1, W1T, C_, H_, b, sm); return; }
    b -= NB_C1;
    if (b < NB_LN) { ln_body(x, gamma, beta, h, b, (float*)sm); return; }
    b -= NB_LN;
    if (b < NB_CNT) { count_body(winners, counts_arr, b, (int*)sm); return; }
    b -= NB_CNT;
    if (b == 0 && threadIdx.x < E_) pos[threadIdx.x] = 0;
    const int p = (b * 256 + threadIdx.x) * 4;  // token_id = -1 fill
    if (p < MAXROWS) *(int4*)(token_id + p) = make_int4(-1, -1, -1, -1);
}

// ---------------- Placement: block-aggregated reservation --------------------
__global__ __launch_bounds__(256) void place_kernel(
    const int* __restrict__ winners, const float* __restrict__ wts,
    const int* __restrict__ counts_arr, int* __restrict__ pos,
    int* __restrict__ token_id, float* __restrict__ pair_w,
    int* __restrict__ tile_expert) {
    __shared__ int po[E_ + 1];
    __shared__ int tot[E_];
    __shared__ int lcount[E_], lbase[E_];
    const int t = threadIdx.x;
    if (t < E_) {
        lcount[t] = 0;
        int c = 0;
        #pragma unroll
        for (int b2 = 0; b2 < NB_CNT; ++b2) c += counts_arr[b2 * E_ + t];
        tot[t] = c;
    }
    __syncthreads();
    if (t == 0) {
        int off = 0;
        po[0] = 0;
        #pragma unroll
        for (int e = 0; e < E_; ++e) {
            off += ((tot[e] + 127) >> 7) << 7;
            po[e + 1] = off;
        }
    }
    __syncthreads();
    if (blockIdx.x == 0 && t < MAXTILES) {
        int r = t * 128;
        int ee = -1;
        if (r < po[E_]) {
            ee = 0;
            while (r >= po[ee + 1]) ++ee;
        }
        tile_expert[t] = ee;
    }
    const int p = blockIdx.x * 256 + t;
    const int e = winners[p];
    const int rank = atomicAdd(&lcount[e], 1);  // LDS atomic
    __syncthreads();
    if (t < E_) {
        int c = lcount[t];
        lbase[t] = c ? atomicAdd(&pos[t], c) : 0;
    }
    __syncthreads();
    const int slot = po[e] + lbase[e] + rank;
    token_id[slot] = p >> 1;
    pair_w[slot] = wts[p];
}

// ---------------- Grouped GEMM body (round-2/4/5 proven; epilogue stores of
// hidden are now NON-TEMPORAL — hidden (131 MB) streams through L2 exactly
// once and was evicting the h/W1T operand panels; per-XCD working set
// arithmetic: 17rt x 128rows x 2KB = 4.3 MB > 4 MB L2) ----------------------
// m97-style async staging + XOR swizzle, 4 blocks/CU implicit wave overlap,
// T1 XCD-bijective swizzle, PHASE2 K-split.
// PHASE2=false: hidden[r,:] = bf16(relu(h[tok(r)] @ W1T[e]^T)^2)  K=1024, N=4096
//               hidden K-dim stored permuted: p64 = lrow*4 + ni
// PHASE2=true : out[tok(r),:] += pair_w[r] * (hidden[r] @ W2T[e]^T) K=4096/KSPLIT
template <bool PHASE2>
__device__ __forceinline__ void gemm_body(
    const u16* __restrict__ Amat, const u16* __restrict__ Bmat,
    const int* __restrict__ token_id, const float* __restrict__ pair_w,
    const int* __restrict__ tile_expert, u16* __restrict__ hidden,
    float* __restrict__ out, const u16* __restrict__ zeropage,
    int bid0, int zi, u16* __restrict__ As, u16* __restrict__ Bs) {
    constexpr int Kdim = PHASE2 ? H_ : C_;            // row pitch of A and B
    constexpr int KRANGE = PHASE2 ? (H_ / KSPLIT) : C_;  // per-block K extent
    constexpr int NWGX = PHASE2 ? (C_ / BN) : (H_ / BN); // 8 or 32
    constexpr int NWG = NWGX * MAXTILES;              // 1088 or 4352 (%8==0)

    int bid = (bid0 & 7) * (NWG >> 3) + (bid0 >> 3);
    const int ct = bid % NWGX;
    const int rt = bid / NWGX;

    const int e = tile_expert[rt];
    if (e < 0) return;
    const int tid = threadIdx.x;
    const int w = tid >> 6;      // wave 0..3
    const int lane = tid & 63;
    const int n0 = ct * BN;
    const int kbase = PHASE2 ? zi * KRANGE : 0;
    const u16* Bb = Bmat + (size_t)e * H_ * C_;

    const int sub = lane >> 3;
    const size_t koffB = (size_t)(((lane & 7) ^ sub) * 16);

    const char* abase[4];
    bool aval[4];
    const char* bbase[4];
    u16* adst[4];
    u16* bdst[4];
    #pragma unroll
    for (int j = 0; j < 4; ++j) {
        const int lrow32 = w * 32 + j * 8 + sub;
        const int grow = rt * BM + lrow32;
        if (PHASE2) {
            aval[j] = true;
            abase[j] = (const char*)(Amat + (size_t)grow * Kdim + kbase) + koffB;
        } else {
            int tok = token_id[grow];
            aval[j] = tok >= 0;
            abase[j] = (const char*)(Amat + (size_t)(tok < 0 ? 0 : tok) * Kdim) + koffB;
        }
        bbase[j] = (const char*)(Bb + (size_t)(n0 + lrow32) * Kdim + kbase) + koffB;
        adst[j] = &As[(w * 32 + j * 8) * BK];
        bdst[j] = &Bs[(w * 32 + j * 8) * BK];
    }

    const int wr = w >> 1, wc = w & 1;
    const int lrow = lane & 15;
    const int quad = lane >> 4;
    const int rsw = lrow & 7;  // read-side swizzle key

    f32x4 acc[4][4] = {};

    for (int k0 = 0; k0 < KRANGE; k0 += BK) {
        __syncthreads();
        const size_t kb = (size_t)k0 * 2;
        #pragma unroll
        for (int j = 0; j < 4; ++j)
            gld16(aval[j] ? abase[j] + kb : (const char*)zeropage, adst[j]);
        #pragma unroll
        for (int j = 0; j < 4; ++j)
            gld16(bbase[j] + kb, bdst[j]);
        __syncthreads();
        #pragma unroll
        for (int kk = 0; kk < 2; ++kk) {
            bf16x8 af[4], bfv[4];
            #pragma unroll
            for (int mi = 0; mi < 4; ++mi) {
                int row = wr * 64 + mi * 16 + lrow;
                int pch = (kk * 4 + quad) ^ rsw;
                af[mi] = *(const bf16x8*)&As[row * BK + pch * 8];
            }
            #pragma unroll
            for (int ni = 0; ni < 4; ++ni) {
                int row = wc * 64 + ni * 16 + lrow;
                int pch = (kk * 4 + quad) ^ rsw;
                bfv[ni] = *(const bf16x8*)&Bs[row * BK + pch * 8];
            }
            #pragma unroll
            for (int mi = 0; mi < 4; ++mi)
                #pragma unroll
                for (int ni = 0; ni < 4; ++ni)
                    acc[mi][ni] = __builtin_amdgcn_mfma_f32_16x16x32_bf16(
                        af[mi], bfv[ni], acc[mi][ni], 0, 0, 0);
        }
    }

    if (!PHASE2) {
        #pragma unroll
        for (int mi = 0; mi < 4; ++mi) {
            int rbase = rt * BM + wr * 64 + mi * 16 + quad * 4;
            #pragma unroll
            for (int j = 0; j < 4; ++j) {
                u16x4 o;
                float v0 = fmaxf(acc[mi][0][j], 0.0f);
                float v1 = fmaxf(acc[mi][1][j], 0.0f);
                float v2 = fmaxf(acc[mi][2][j], 0.0f);
                float v3 = fmaxf(acc[mi][3][j], 0.0f);
                o[0] = f2bf(v0 * v0);
                o[1] = f2bf(v1 * v1);
                o[2] = f2bf(v2 * v2);
                o[3] = f2bf(v3 * v3);
                __builtin_nontemporal_store(
                    o, (u16x4*)&hidden[(size_t)(rbase + j) * H_ + n0 +
                                       wc * 64 + lrow * 4]);
            }
        }
    } else {
        #pragma unroll
        for (int mi = 0; mi < 4; ++mi) {
            int rbase = rt * BM + wr * 64 + mi * 16 + quad * 4;
            #pragma unroll
            for (int j = 0; j < 4; ++j) {
                int grow = rbase + j;
                int tok = token_id[grow];
                if (tok < 0) continue;
                float pw = pair_w[grow];
                #pragma unroll
                for (int ni = 0; ni < 4; ++ni) {
                    int col = n0 + wc * 64 + ni * 16 + lrow;
                    atomicAdd(&out[(size_t)tok * C_ + col], pw * acc[mi][ni][j]);
                }
            }
        }
    }
}

// ---------------- gemm1 + conv-W2 + out=x soak (horizontal fusion) -----------
// conv-W2 and the residual copy only gate gemm2; gemm1 uses ~16% of HBM BW,
// so their ~256 MB streams free under gemm1's compute. LDS union = 32 KB.
__global__ __launch_bounds__(256, 4) void gemm1_conv(
    const u16* __restrict__ h, const u16* __restrict__ W1T,
    const int* __restrict__ token_id, const float* __restrict__ pair_w,
    const int* __restrict__ tile_expert, u16* __restrict__ hidden,
    const u16* __restrict__ zeropage, const float* __restrict__ W2,
    u16* __restrict__ W2T, const float* __restrict__ x,
    float* __restrict__ out) {
    __shared__ u16 smu[2 * BM * BK];  // 32 KB: gemm As+Bs; conv uses 16.6 KB
    const int b = blockIdx.x;
    if (b < NWG1) {
        gemm_body<false>(h, W1T, token_id, pair_w, tile_expert, hidden,
                         nullptr, zeropage, b, 0, smu, smu + BM * BK);
    } else if (b < NWG1 + NB_C2) {
        conv_body<true>(W2, W2T, H_, C_, b - NWG1, smu);
    } else {
        copy_body(x, out, b - NWG1 - NB_C2);
    }
}

// ---------------- phase2 wrapper: LB(256,4) — 5/CU spills (R10 post-mortem:
// acc alone needs 64 VGPR; 5 waves/SIMD caps ~102 total -> scratch, 2.2x) ----
__global__ __launch_bounds__(256, 4) void gemm2_kernel(
    const u16* __restrict__ hidden, const u16* __restrict__ W2T,
    const int* __restrict__ token_id, const float* __restrict__ pair_w,
    const int* __restrict__ tile_expert, float* __restrict__ out,
    const u16* __restrict__ zeropage) {
    __shared__ u16 As[BM * BK];
    __shared__ u16 Bs[BN * BK];
    const int bid = blockIdx.y * (C_ / BN) + blockIdx.x;
    gemm_body<true>(hidden, W2T, token_id, pair_w, tile_expert, nullptr, out,
                    zeropage, bid, blockIdx.z, As, Bs);
}

// ---------------- Launch ----------------
extern "C" void kernel_launch(void* const* d_in, const int* in_sizes, int n_in,
                              void* d_out, int out_size, void* d_ws, size_t ws_size,
                              hipStream_t stream) {
    const float* x = (const float*)d_in[0];
    const float* weights = (const float*)d_in[1];
    const float* gamma = (const float*)d_in[2];
    const float* beta = (const float*)d_in[3];
    const float* W1 = (const float*)d_in[4];
    const float* W2 = (const float*)d_in[5];
    const int* winners = (const int*)d_in[6];
    float* out = (float*)d_out;

    char* ws = (char*)d_ws;
    const size_t SZ_H = (size_t)NTOK * C_ * 2;           // 16 MB
    const size_t SZ_HID = (size_t)MAXROWS * H_ * 2;      // 136 MB
    const size_t SZ_WT = (size_t)E_ * H_ * C_ * 2;       // 64 MB each
    const size_t OFF_HID = SZ_H;
    const size_t OFF_W1T = OFF_HID + SZ_HID;
    const size_t OFF_W2T = OFF_W1T + SZ_WT;
    const size_t OFF_META = OFF_W2T + SZ_WT;

    u16* h = (u16*)ws;
    u16* hidden = (u16*)(ws + OFF_HID);
    u16* W1T = (u16*)(ws + OFF_W1T);
    u16* W2T = (u16*)(ws + OFF_W2T);
    int* meta = (int*)(ws + OFF_META);
    int* pos = meta + 8;                // [8,16)
    u16* zeropage = (u16*)(meta + 32);  // [32,48) 64 B region, 16B-aligned
                                        // (contents row-isolated -> no zeroing)
    int* tile_expert = meta + 48;       // [48,184), fully rewritten each run
    int* counts_arr = meta + 192;       // [192,704): 64 blocks x 8 experts
    int* token_id = meta + 704;         // 16B-aligned (704*4 = 2816)
    float* pair_w = (float*)(meta + 704 + MAXROWS);

    fused_pre<<<NB_TOTAL, 256, 0, stream>>>(x, gamma, beta, h, winners,
                                            counts_arr, W1, W1T, token_id, pos);
    place_kernel<<<NPAIR / 256, 256, 0, stream>>>(winners, weights, counts_arr,
                                                  pos, token_id, pair_w,
                                                  tile_expert);
    gemm1_conv<<<NWG1 + NB_C2 + NB_CP, 256, 0, stream>>>(
        h, W1T, token_id, pair_w, tile_expert, hidden, zeropage, W2, W2T, x, out);
    gemm2_kernel<<<dim3(C_ / BN, MAXTILES, KSPLIT), 256, 0, stream>>>(
        hidden, W2T, token_id, pair_w, tile_expert, out, zeropage);
}